// Round 2
// baseline (337.797 us; speedup 1.0000x reference)
//
#include <hip/hip_runtime.h>
#include <cstdint>

#define DIM 768
#define NHEAD 12
#define HDIM 64
#define SEQ 1024
#define BATCH 8

typedef __attribute__((ext_vector_type(8))) short bf16x8;
typedef __attribute__((ext_vector_type(4))) float f32x4;
typedef __attribute__((ext_vector_type(16))) float f32x16;

__device__ __forceinline__ unsigned short f2bf(float f) {
  unsigned int u = __float_as_uint(f);
  return (unsigned short)((u + 0x7FFFu + ((u >> 16) & 1u)) >> 16);
}
__device__ __forceinline__ float bf2f(unsigned short h) {
  return __uint_as_float(((unsigned int)h) << 16);
}
__device__ __forceinline__ void gl_lds16(const void* g, void* l) {
  __builtin_amdgcn_global_load_lds(
      (const __attribute__((address_space(1))) unsigned int*)g,
      (__attribute__((address_space(3))) unsigned int*)l, 16, 0, 0);
}

// ---------------------------------------------------------------------------
// prep_x: x fp32 [8192][768] -> A1' bf16 [8192][2304] = [xh | xl | xh]
// ---------------------------------------------------------------------------
__global__ __launch_bounds__(256) void prep_x(const float* __restrict__ x,
                                              unsigned short* __restrict__ a1) {
  int gid = blockIdx.x * 256 + threadIdx.x;  // 8192*192
  int m = gid / 192;
  int c = (gid % 192) * 4;
  float4 v = *(const float4*)&x[(size_t)m * DIM + c];
  float vv[4] = {v.x, v.y, v.z, v.w};
  unsigned int hi0, hi1, lo0, lo1;
  unsigned short h[4], lo[4];
#pragma unroll
  for (int i = 0; i < 4; ++i) {
    h[i] = f2bf(vv[i]);
    lo[i] = f2bf(vv[i] - bf2f(h[i]));
  }
  hi0 = (unsigned)h[0] | ((unsigned)h[1] << 16);
  hi1 = (unsigned)h[2] | ((unsigned)h[3] << 16);
  lo0 = (unsigned)lo[0] | ((unsigned)lo[1] << 16);
  lo1 = (unsigned)lo[2] | ((unsigned)lo[3] << 16);
  size_t r = (size_t)m * 2304;
  *(uint2*)&a1[r + c] = make_uint2(hi0, hi1);
  *(uint2*)&a1[r + 768 + c] = make_uint2(lo0, lo1);
  *(uint2*)&a1[r + 1536 + c] = make_uint2(hi0, hi1);
}

// ---------------------------------------------------------------------------
// prep_wt: w fp32 [768][N] -> wt bf16 [N][2304] rows = [wh^T | wh^T | wl^T]
// ---------------------------------------------------------------------------
__global__ __launch_bounds__(256) void prep_wt(const float* __restrict__ w,
                                               unsigned short* __restrict__ wt,
                                               int N) {
  __shared__ float tile[32][33];  // tile[n_local][k_local]
  int kt = blockIdx.x * 32;
  int nt = blockIdx.y * 32;
  int t = threadIdx.x;
  int c = t & 31, r8 = t >> 5;
#pragma unroll
  for (int p = 0; p < 4; ++p) {
    int k = kt + p * 8 + r8;
    tile[c][p * 8 + r8] = w[(size_t)k * N + nt + c];
  }
  __syncthreads();
#pragma unroll
  for (int p = 0; p < 4; ++p) {
    int nl = p * 8 + r8;
    float f = tile[nl][c];
    unsigned short h = f2bf(f), l = f2bf(f - bf2f(h));
    size_t row = (size_t)(nt + nl) * 2304 + kt + c;
    wt[row] = h;
    wt[row + 768] = h;
    wt[row + 1536] = l;
  }
}

// ---------------------------------------------------------------------------
// Plain bf16 GEMM (m97 structure): C[M,N] = A'[M,Kp] x Bt[N,Kp]^T.
// 128x128 tile, BK=64, 4 waves (2x2), 16x16x32 MFMA, XOR-swizzled LDS,
// global_load_lds width-16 staging with pre-permuted source.
// EPI 0: fp32 C + bias. EPI 1: split-write qh/ql/kh/kl/vt (QKV epilogue).
// ---------------------------------------------------------------------------
template <int EPI>
__global__ __launch_bounds__(256) void gemm_bf16(
    const unsigned short* __restrict__ A, const unsigned short* __restrict__ Bt,
    const float* __restrict__ bias, float* __restrict__ C,
    unsigned short* __restrict__ qh, unsigned short* __restrict__ ql,
    unsigned short* __restrict__ kh, unsigned short* __restrict__ kl,
    unsigned short* __restrict__ vt, int N, int Kp) {
  __shared__ char As[16384];  // 128 rows x 128 B
  __shared__ char Bs[16384];
  const int t = threadIdx.x;
  const int l = t & 63, wv = t >> 6;
  const int g = l >> 4, l15 = l & 15;
  const int wr = wv >> 1, wc = wv & 1;
  const int m0 = blockIdx.y * 128, n0 = blockIdx.x * 128;

  f32x4 acc[4][4];
#pragma unroll
  for (int i = 0; i < 4; ++i)
#pragma unroll
    for (int j = 0; j < 4; ++j)
#pragma unroll
      for (int r = 0; r < 4; ++r) acc[i][j][r] = 0.f;

  const int rowr = t >> 3;                    // 0..31
  const int dc = ((t & 7) ^ (rowr & 7)) * 8;  // source element offset (swizzle)

  for (int k0 = 0; k0 < Kp; k0 += 64) {
    __syncthreads();
#pragma unroll
    for (int p = 0; p < 4; ++p) {
      int row = p * 32 + rowr;
      gl_lds16(A + (size_t)(m0 + row) * Kp + k0 + dc, As + p * 4096 + wv * 1024);
      gl_lds16(Bt + (size_t)(n0 + row) * Kp + k0 + dc, Bs + p * 4096 + wv * 1024);
    }
    __syncthreads();
#pragma unroll
    for (int ks = 0; ks < 2; ++ks) {
      bf16x8 af[4], bfr[4];
#pragma unroll
      for (int mf = 0; mf < 4; ++mf) {
        int row = wr * 64 + mf * 16 + l15;
        af[mf] = *(const bf16x8*)(As + row * 128 + ((ks * 4 + g) ^ (row & 7)) * 16);
      }
#pragma unroll
      for (int nf = 0; nf < 4; ++nf) {
        int row = wc * 64 + nf * 16 + l15;
        bfr[nf] = *(const bf16x8*)(Bs + row * 128 + ((ks * 4 + g) ^ (row & 7)) * 16);
      }
#pragma unroll
      for (int mf = 0; mf < 4; ++mf)
#pragma unroll
        for (int nf = 0; nf < 4; ++nf)
          acc[mf][nf] = __builtin_amdgcn_mfma_f32_16x16x32_bf16(
              af[mf], bfr[nf], acc[mf][nf], 0, 0, 0);
    }
  }

  if (EPI == 0) {
#pragma unroll
    for (int mf = 0; mf < 4; ++mf) {
      int row = m0 + wr * 64 + mf * 16 + g * 4;
#pragma unroll
      for (int nf = 0; nf < 4; ++nf) {
        int col = n0 + wc * 64 + nf * 16 + l15;
        float bb = bias[col];
#pragma unroll
        for (int r = 0; r < 4; ++r)
          C[(size_t)(row + r) * N + col] = acc[mf][nf][r] + bb;
      }
    }
  } else {
    const int region = blockIdx.x / 6;  // 0=q, 1=k, 2=v
    const int colr0 = (blockIdx.x % 6) * 128;
#pragma unroll
    for (int mf = 0; mf < 4; ++mf) {
      int m = m0 + wr * 64 + mf * 16 + g * 4;
      int b = m >> 10, ns = m & 1023;
#pragma unroll
      for (int nf = 0; nf < 4; ++nf) {
        int colr = colr0 + wc * 64 + nf * 16 + l15;
        int hh = colr >> 6, d = colr & 63;
        size_t base = ((size_t)(b * NHEAD + hh)) << 16;
        if (region == 0) {
#pragma unroll
          for (int r = 0; r < 4; ++r) {
            float v = acc[mf][nf][r] * 0.125f;
            unsigned short hi = f2bf(v);
            size_t idx = base + ((size_t)(ns + r) << 6) + d;
            qh[idx] = hi;
            ql[idx] = f2bf(v - bf2f(hi));
          }
        } else if (region == 1) {
#pragma unroll
          for (int r = 0; r < 4; ++r) {
            float v = acc[mf][nf][r];
            unsigned short hi = f2bf(v);
            size_t idx = base + ((size_t)(ns + r) << 6) + d;
            kh[idx] = hi;
            kl[idx] = f2bf(v - bf2f(hi));
          }
        } else {
          unsigned int w0 = (unsigned)f2bf(acc[mf][nf][0]) |
                            ((unsigned)f2bf(acc[mf][nf][1]) << 16);
          unsigned int w1 = (unsigned)f2bf(acc[mf][nf][2]) |
                            ((unsigned)f2bf(acc[mf][nf][3]) << 16);
          *(uint2*)(vt + base + ((size_t)d << 10) + ns) = make_uint2(w0, w1);
        }
      }
    }
  }
}

// ---------------------------------------------------------------------------
// Taylor attention: per (b,h). Block = 4 waves x 32 q-rows = 128 q-rows.
// Swapped QK^T (mfma(K,Q), 32x32x16) -> lane-local P row; f(s) in fp32;
// P->bf16 + shfl_xor(32) half-swap feeds PV A-operand. V staged transposed.
// Output written as A2' bf16 [8192][2304] = [oh | ol | oh].
// ---------------------------------------------------------------------------
__global__ __launch_bounds__(256) void attn(
    const unsigned short* __restrict__ qh, const unsigned short* __restrict__ ql,
    const unsigned short* __restrict__ kh, const unsigned short* __restrict__ kl,
    const unsigned short* __restrict__ vt, unsigned short* __restrict__ a2) {
  __shared__ char KH[8192], KL[8192], VT[8192];  // [64 rows][128 B], swizzled
  __shared__ float DEN[4][32];
  const int t = threadIdx.x;
  const int l = t & 63, wv = t >> 6;
  const int h = l >> 5, l31 = l & 31;
  const int bh = blockIdx.y;
  const int q0 = blockIdx.x * 128 + wv * 32;
  const size_t hb = ((size_t)bh) << 16;

  bf16x8 qhf[4], qlf[4];
#pragma unroll
  for (int ks = 0; ks < 4; ++ks) {
    size_t off = hb + ((size_t)(q0 + l31) << 6) + ks * 16 + h * 8;
    qhf[ks] = *(const bf16x8*)(qh + off);
    qlf[ks] = *(const bf16x8*)(ql + off);
  }

  f32x16 o0, o1;
#pragma unroll
  for (int r = 0; r < 16; ++r) { o0[r] = 0.f; o1[r] = 0.f; }
  float den = 0.f;

  const int rowr = t >> 3;
  const int dc = ((t & 7) ^ (rowr & 7)) * 8;

  for (int kt = 0; kt < 16; ++kt) {
    const int j0 = kt * 64;
    __syncthreads();
#pragma unroll
    for (int p = 0; p < 2; ++p) {
      int row = p * 32 + rowr;
      gl_lds16(kh + hb + ((size_t)(j0 + row) << 6) + dc, KH + p * 4096 + wv * 1024);
      gl_lds16(kl + hb + ((size_t)(j0 + row) << 6) + dc, KL + p * 4096 + wv * 1024);
      gl_lds16(vt + hb + ((size_t)row << 10) + j0 + dc, VT + p * 4096 + wv * 1024);
    }
    __syncthreads();

    // S' = K . Q^T  (rows j, cols i), hi/lo split on both operands (3 passes)
    f32x16 sf0, sf1;
#pragma unroll
    for (int r = 0; r < 16; ++r) { sf0[r] = 0.f; sf1[r] = 0.f; }
#pragma unroll
    for (int ks = 0; ks < 4; ++ks) {
      const int ch = ((2 * ks + h) ^ (l31 & 7)) * 16;
      {
        const bf16x8 k_h = *(const bf16x8*)(KH + l31 * 128 + ch);
        const bf16x8 k_l = *(const bf16x8*)(KL + l31 * 128 + ch);
        sf0 = __builtin_amdgcn_mfma_f32_32x32x16_bf16(k_h, qhf[ks], sf0, 0, 0, 0);
        sf0 = __builtin_amdgcn_mfma_f32_32x32x16_bf16(k_l, qhf[ks], sf0, 0, 0, 0);
        sf0 = __builtin_amdgcn_mfma_f32_32x32x16_bf16(k_h, qlf[ks], sf0, 0, 0, 0);
      }
      {
        const bf16x8 k_h = *(const bf16x8*)(KH + (32 + l31) * 128 + ch);
        const bf16x8 k_l = *(const bf16x8*)(KL + (32 + l31) * 128 + ch);
        sf1 = __builtin_amdgcn_mfma_f32_32x32x16_bf16(k_h, qhf[ks], sf1, 0, 0, 0);
        sf1 = __builtin_amdgcn_mfma_f32_32x32x16_bf16(k_l, qhf[ks], sf1, 0, 0, 0);
        sf1 = __builtin_amdgcn_mfma_f32_32x32x16_bf16(k_h, qlf[ks], sf1, 0, 0, 0);
      }
    }

    // f(s) = 1 + s + 0.5 s^2  (>= 0.5, ReLU no-op); pack quads as bf16
    unsigned int qw[8][2];
#pragma unroll
    for (int jf = 0; jf < 2; ++jf) {
#pragma unroll
      for (int q = 0; q < 4; ++q) {
        float f[4];
#pragma unroll
        for (int e = 0; e < 4; ++e) {
          float s = (jf == 0) ? sf0[q * 4 + e] : sf1[q * 4 + e];
          f[e] = fmaf(s, fmaf(s, 0.5f, 1.0f), 1.0f);
          den += f[e];
        }
        qw[jf * 4 + q][0] = (unsigned)f2bf(f[0]) | ((unsigned)f2bf(f[1]) << 16);
        qw[jf * 4 + q][1] = (unsigned)f2bf(f[2]) | ((unsigned)f2bf(f[3]) << 16);
      }
    }

    // PV: build pa[ks] via half-swap, multiply with transposed V tile
#pragma unroll
    for (int ks = 0; ks < 4; ++ks) {
      unsigned int u00 = qw[2 * ks][0], u01 = qw[2 * ks][1];
      unsigned int u10 = qw[2 * ks + 1][0], u11 = qw[2 * ks + 1][1];
      unsigned int s00 = (unsigned)__shfl_xor((int)u00, 32, 64);
      unsigned int s01 = (unsigned)__shfl_xor((int)u01, 32, 64);
      unsigned int s10 = (unsigned)__shfl_xor((int)u10, 32, 64);
      unsigned int s11 = (unsigned)__shfl_xor((int)u11, 32, 64);
      union { unsigned int u[4]; bf16x8 v; } pu;
      pu.u[0] = h ? s10 : u00;
      pu.u[1] = h ? s11 : u01;
      pu.u[2] = h ? u10 : s00;
      pu.u[3] = h ? u11 : s01;
      {
        const bf16x8 vb =
            *(const bf16x8*)(VT + l31 * 128 + (((2 * ks + h) ^ (l31 & 7)) * 16));
        o0 = __builtin_amdgcn_mfma_f32_32x32x16_bf16(pu.v, vb, o0, 0, 0, 0);
      }
      {
        const int row = 32 + l31;
        const bf16x8 vb =
            *(const bf16x8*)(VT + row * 128 + (((2 * ks + h) ^ (row & 7)) * 16));
        o1 = __builtin_amdgcn_mfma_f32_32x32x16_bf16(pu.v, vb, o1, 0, 0, 0);
      }
    }
  }

  // denominator: combine h-halves, share via LDS (per-wave region)
  den += __shfl_xor(den, 32, 64);
  if (h == 0) DEN[wv][l31] = den;
  __syncthreads();

  const int bq = (bh / NHEAD) * SEQ + q0;
  const int c0 = (bh % NHEAD) * HDIM;
#pragma unroll
  for (int r = 0; r < 16; ++r) {
    const int i = (r & 3) + 8 * (r >> 2) + 4 * h;
    const float inv = 1.0f / DEN[wv][i];
    const float v0 = o0[r] * inv, v1 = o1[r] * inv;
    const size_t row = (size_t)(bq + i) * 2304;
    const unsigned short h0 = f2bf(v0), h1 = f2bf(v1);
    a2[row + c0 + l31] = h0;
    a2[row + 768 + c0 + l31] = f2bf(v0 - bf2f(h0));
    a2[row + 1536 + c0 + l31] = h0;
    a2[row + c0 + l31 + 32] = h1;
    a2[row + 768 + c0 + l31 + 32] = f2bf(v1 - bf2f(h1));
    a2[row + 1536 + c0 + l31 + 32] = h1;
  }
}

// ---------------------------------------------------------------------------
extern "C" void kernel_launch(void* const* d_in, const int* in_sizes, int n_in,
                              void* d_out, int out_size, void* d_ws,
                              size_t ws_size, hipStream_t stream) {
  const float* x = (const float*)d_in[0];
  const float* w_qkv = (const float*)d_in[1];
  const float* w_proj = (const float*)d_in[2];
  const float* b_proj = (const float*)d_in[3];
  float* out = (float*)d_out;

  unsigned short* W1t = (unsigned short*)d_ws;        // [2304][2304]
  unsigned short* W2t = W1t + (size_t)2304 * 2304;    // [768][2304]
  unsigned short* A1 = W2t + (size_t)768 * 2304;      // [8192][2304] (also A2')
  unsigned short* qh = A1 + (size_t)8192 * 2304;      // [96][1024][64]
  unsigned short* ql = qh + (size_t)96 * 65536;
  unsigned short* kh = ql + (size_t)96 * 65536;
  unsigned short* kl = kh + (size_t)96 * 65536;
  unsigned short* vt = kl + (size_t)96 * 65536;       // [96][64][1024]

  prep_x<<<6144, 256, 0, stream>>>(x, A1);
  prep_wt<<<dim3(24, 72), 256, 0, stream>>>(w_qkv, W1t, 2304);
  prep_wt<<<dim3(24, 24), 256, 0, stream>>>(w_proj, W2t, 768);

  // qkv = A1' x W1t^T, epilogue splits into qh/ql/kh/kl/vt
  gemm_bf16<1><<<dim3(18, 64), 256, 0, stream>>>(A1, W1t, nullptr, nullptr, qh,
                                                 ql, kh, kl, vt, 2304, 2304);

  // attention -> A2' (aliases A1, fully overwritten)
  attn<<<dim3(8, 96), 256, 0, stream>>>(qh, ql, kh, kl, vt, A1);

  // out = A2' x W2t^T + bias
  gemm_bf16<0><<<dim3(6, 64), 256, 0, stream>>>(A1, W2t, b_proj, out, nullptr,
                                                nullptr, nullptr, nullptr,
                                                nullptr, 768, 2304);
}

// Round 3
// 207.320 us; speedup vs baseline: 1.6293x; 1.6293x over previous
//
#include <hip/hip_runtime.h>
#include <cstdint>

#define DIM 768
#define NHEAD 12
#define SEQ 1024
#define BATCH 8

typedef _Float16 f16x8 __attribute__((ext_vector_type(8)));
typedef __attribute__((ext_vector_type(4))) float f32x4;
typedef __attribute__((ext_vector_type(16))) float f32x16;

__device__ __forceinline__ unsigned short f2hu(float f) {
  union { _Float16 h; unsigned short u; } x;
  x.h = (_Float16)f;
  return x.u;
}
__device__ __forceinline__ unsigned int pk2(float a, float b) {
  union { _Float16 h[2]; unsigned int u; } x;
  x.h[0] = (_Float16)a;
  x.h[1] = (_Float16)b;
  return x.u;
}
__device__ __forceinline__ void gl_lds16(const void* g, void* l) {
  __builtin_amdgcn_global_load_lds(
      (const __attribute__((address_space(1))) unsigned int*)g,
      (__attribute__((address_space(3))) unsigned int*)l, 16, 0, 0);
}

// ---------------------------------------------------------------------------
// prep_x: x fp32 [8192][768] -> A1 fp16 [8192][768]
// ---------------------------------------------------------------------------
__global__ __launch_bounds__(256) void prep_x(const float* __restrict__ x,
                                              unsigned short* __restrict__ a1) {
  int gid = blockIdx.x * 256 + threadIdx.x;  // 8192*192
  int m = gid / 192;
  int c = (gid % 192) * 4;
  float4 v = *(const float4*)&x[(size_t)m * DIM + c];
  *(uint2*)&a1[(size_t)m * DIM + c] = make_uint2(pk2(v.x, v.y), pk2(v.z, v.w));
}

// ---------------------------------------------------------------------------
// prep_wt: w fp32 [768][N] -> wt fp16 [N][768] (transposed)
// ---------------------------------------------------------------------------
__global__ __launch_bounds__(256) void prep_wt(const float* __restrict__ w,
                                               unsigned short* __restrict__ wt,
                                               int N) {
  __shared__ float tile[32][33];
  int kt = blockIdx.x * 32;
  int nt = blockIdx.y * 32;
  int t = threadIdx.x;
  int c = t & 31, r8 = t >> 5;
#pragma unroll
  for (int p = 0; p < 4; ++p) {
    int k = kt + p * 8 + r8;
    tile[c][p * 8 + r8] = w[(size_t)k * N + nt + c];
  }
  __syncthreads();
#pragma unroll
  for (int p = 0; p < 4; ++p) {
    int nl = p * 8 + r8;
    wt[(size_t)(nt + nl) * DIM + kt + c] = f2hu(tile[nl][c]);
  }
}

// ---------------------------------------------------------------------------
// fp16 GEMM (m97 structure): C[M,N] = A[M,768] x Bt[N,768]^T.
// 128x128 tile, BK=64, 4 waves (2x2), 16x16x32 MFMA, XOR-swizzled LDS,
// global_load_lds width-16 staging with pre-permuted source.
// EPI 0: fp32 C + bias. EPI 1: QKV epilogue -> q(scaled)/k/vt fp16.
// ---------------------------------------------------------------------------
template <int EPI>
__global__ __launch_bounds__(256) void gemm_f16(
    const unsigned short* __restrict__ A, const unsigned short* __restrict__ Bt,
    const float* __restrict__ bias, float* __restrict__ C,
    unsigned short* __restrict__ q, unsigned short* __restrict__ k,
    unsigned short* __restrict__ vt, int N) {
  __shared__ char As[16384];  // 128 rows x 128 B
  __shared__ char Bs[16384];
  const int t = threadIdx.x;
  const int l = t & 63, wv = t >> 6;
  const int g = l >> 4, l15 = l & 15;
  const int wr = wv >> 1, wc = wv & 1;
  const int m0 = blockIdx.y * 128, n0 = blockIdx.x * 128;

  f32x4 acc[4][4];
#pragma unroll
  for (int i = 0; i < 4; ++i)
#pragma unroll
    for (int j = 0; j < 4; ++j)
#pragma unroll
      for (int r = 0; r < 4; ++r) acc[i][j][r] = 0.f;

  const int rowr = t >> 3;                    // 0..31
  const int dc = ((t & 7) ^ (rowr & 7)) * 8;  // swizzled source offset (elems)

  for (int k0 = 0; k0 < DIM; k0 += 64) {
    __syncthreads();
#pragma unroll
    for (int p = 0; p < 4; ++p) {
      int row = p * 32 + rowr;
      gl_lds16(A + (size_t)(m0 + row) * DIM + k0 + dc, As + p * 4096 + wv * 1024);
      gl_lds16(Bt + (size_t)(n0 + row) * DIM + k0 + dc, Bs + p * 4096 + wv * 1024);
    }
    __syncthreads();
#pragma unroll
    for (int ks = 0; ks < 2; ++ks) {
      f16x8 af[4], bfr[4];
#pragma unroll
      for (int mf = 0; mf < 4; ++mf) {
        int row = wr * 64 + mf * 16 + l15;
        af[mf] = *(const f16x8*)(As + row * 128 + ((ks * 4 + g) ^ (row & 7)) * 16);
      }
#pragma unroll
      for (int nf = 0; nf < 4; ++nf) {
        int row = wc * 64 + nf * 16 + l15;
        bfr[nf] = *(const f16x8*)(Bs + row * 128 + ((ks * 4 + g) ^ (row & 7)) * 16);
      }
#pragma unroll
      for (int mf = 0; mf < 4; ++mf)
#pragma unroll
        for (int nf = 0; nf < 4; ++nf)
          acc[mf][nf] = __builtin_amdgcn_mfma_f32_16x16x32_f16(
              af[mf], bfr[nf], acc[mf][nf], 0, 0, 0);
    }
  }

  if (EPI == 0) {
#pragma unroll
    for (int mf = 0; mf < 4; ++mf) {
      int row = m0 + wr * 64 + mf * 16 + g * 4;
#pragma unroll
      for (int nf = 0; nf < 4; ++nf) {
        int col = n0 + wc * 64 + nf * 16 + l15;
        float bb = bias[col];
#pragma unroll
        for (int r = 0; r < 4; ++r)
          C[(size_t)(row + r) * N + col] = acc[mf][nf][r] + bb;
      }
    }
  } else {
    const int region = blockIdx.x / 6;  // 0=q, 1=k, 2=v
    const int colr0 = (blockIdx.x % 6) * 128;
#pragma unroll
    for (int mf = 0; mf < 4; ++mf) {
      int m = m0 + wr * 64 + mf * 16 + g * 4;
      int b = m >> 10, ns = m & 1023;
#pragma unroll
      for (int nf = 0; nf < 4; ++nf) {
        int colr = colr0 + wc * 64 + nf * 16 + l15;
        int hh = colr >> 6, d = colr & 63;
        size_t base = ((size_t)(b * NHEAD + hh)) << 16;
        if (region == 0) {
#pragma unroll
          for (int r = 0; r < 4; ++r)
            q[base + ((size_t)(ns + r) << 6) + d] = f2hu(acc[mf][nf][r] * 0.125f);
        } else if (region == 1) {
#pragma unroll
          for (int r = 0; r < 4; ++r)
            k[base + ((size_t)(ns + r) << 6) + d] = f2hu(acc[mf][nf][r]);
        } else {
          *(uint2*)(vt + base + ((size_t)d << 10) + ns) =
              make_uint2(pk2(acc[mf][nf][0], acc[mf][nf][1]),
                         pk2(acc[mf][nf][2], acc[mf][nf][3]));
        }
      }
    }
  }
}

// ---------------------------------------------------------------------------
// Taylor attention, fp16 single pass. Per (b,h); block = 4 waves x 32 q-rows.
// Swapped QK^T (mfma(K,Q), 32x32x16) -> lane-local P column; f(s) in fp32
// (f >= 0.5 so ReLU is a no-op, denominator is a plain running sum);
// P -> fp16 + shfl_xor(32) half-swap feeds PV A-operand; V staged transposed.
// Output: A2 fp16 [8192][768].
// ---------------------------------------------------------------------------
__global__ __launch_bounds__(256) void attn(
    const unsigned short* __restrict__ q, const unsigned short* __restrict__ k,
    const unsigned short* __restrict__ vt, unsigned short* __restrict__ a2) {
  __shared__ char KH[8192], VT[8192];  // [64 rows][128 B], swizzled
  __shared__ float DEN[4][32];
  const int t = threadIdx.x;
  const int l = t & 63, wv = t >> 6;
  const int h = l >> 5, l31 = l & 31;
  const int bh = blockIdx.y;
  const int q0 = blockIdx.x * 128 + wv * 32;
  const size_t hb = ((size_t)bh) << 16;

  f16x8 qf[4];
#pragma unroll
  for (int ks = 0; ks < 4; ++ks)
    qf[ks] = *(const f16x8*)(q + hb + ((size_t)(q0 + l31) << 6) + ks * 16 + h * 8);

  f32x16 o0, o1;
#pragma unroll
  for (int r = 0; r < 16; ++r) { o0[r] = 0.f; o1[r] = 0.f; }
  float den = 0.f;

  const int rowr = t >> 3;
  const int dc = ((t & 7) ^ (rowr & 7)) * 8;

  for (int kt = 0; kt < 16; ++kt) {
    const int j0 = kt * 64;
    __syncthreads();
#pragma unroll
    for (int p = 0; p < 2; ++p) {
      int row = p * 32 + rowr;
      gl_lds16(k + hb + ((size_t)(j0 + row) << 6) + dc, KH + p * 4096 + wv * 1024);
      gl_lds16(vt + hb + ((size_t)row << 10) + j0 + dc, VT + p * 4096 + wv * 1024);
    }
    __syncthreads();

    // S' = K . Q^T (rows j, cols i)
    f32x16 sf0, sf1;
#pragma unroll
    for (int r = 0; r < 16; ++r) { sf0[r] = 0.f; sf1[r] = 0.f; }
#pragma unroll
    for (int ks = 0; ks < 4; ++ks) {
      const int ch = ((2 * ks + h) ^ (l31 & 7)) * 16;
      sf0 = __builtin_amdgcn_mfma_f32_32x32x16_f16(
          *(const f16x8*)(KH + l31 * 128 + ch), qf[ks], sf0, 0, 0, 0);
      const int ch1 = ((2 * ks + h) ^ ((32 + l31) & 7)) * 16;
      sf1 = __builtin_amdgcn_mfma_f32_32x32x16_f16(
          *(const f16x8*)(KH + (32 + l31) * 128 + ch1), qf[ks], sf1, 0, 0, 0);
    }

    // f(s) = 1 + s + 0.5 s^2 (>= 0.5, ReLU no-op); pack to fp16 pairs
    unsigned int qw[8][2];
#pragma unroll
    for (int jf = 0; jf < 2; ++jf) {
#pragma unroll
      for (int qd = 0; qd < 4; ++qd) {
        float f[4];
#pragma unroll
        for (int e = 0; e < 4; ++e) {
          float s = (jf == 0) ? sf0[qd * 4 + e] : sf1[qd * 4 + e];
          f[e] = fmaf(s, fmaf(s, 0.5f, 1.0f), 1.0f);
          den += f[e];
        }
        qw[jf * 4 + qd][0] = pk2(f[0], f[1]);
        qw[jf * 4 + qd][1] = pk2(f[2], f[3]);
      }
    }

    // PV: assemble A-fragment via half-swap, multiply with transposed V tile
#pragma unroll
    for (int ks = 0; ks < 4; ++ks) {
      unsigned int u00 = qw[2 * ks][0], u01 = qw[2 * ks][1];
      unsigned int u10 = qw[2 * ks + 1][0], u11 = qw[2 * ks + 1][1];
      unsigned int s00 = (unsigned)__shfl_xor((int)u00, 32, 64);
      unsigned int s01 = (unsigned)__shfl_xor((int)u01, 32, 64);
      unsigned int s10 = (unsigned)__shfl_xor((int)u10, 32, 64);
      unsigned int s11 = (unsigned)__shfl_xor((int)u11, 32, 64);
      union { unsigned int u[4]; f16x8 v; } pu;
      pu.u[0] = h ? s10 : u00;
      pu.u[1] = h ? s11 : u01;
      pu.u[2] = h ? u10 : s00;
      pu.u[3] = h ? u11 : s01;
      {
        const f16x8 vb =
            *(const f16x8*)(VT + l31 * 128 + (((2 * ks + h) ^ (l31 & 7)) * 16));
        o0 = __builtin_amdgcn_mfma_f32_32x32x16_f16(pu.v, vb, o0, 0, 0, 0);
      }
      {
        const int row = 32 + l31;
        const f16x8 vb =
            *(const f16x8*)(VT + row * 128 + (((2 * ks + h) ^ (row & 7)) * 16));
        o1 = __builtin_amdgcn_mfma_f32_32x32x16_f16(pu.v, vb, o1, 0, 0, 0);
      }
    }
  }

  // denominator: combine halves, share via LDS (per-wave region)
  den += __shfl_xor(den, 32, 64);
  if (h == 0) DEN[wv][l31] = den;
  __syncthreads();

  const int bq = (bh / NHEAD) * SEQ + q0;
  const int c0 = (bh % NHEAD) * 64;
#pragma unroll
  for (int r = 0; r < 16; ++r) {
    const int i = (r & 3) + 8 * (r >> 2) + 4 * h;
    const float inv = 1.0f / DEN[wv][i];
    const size_t row = (size_t)(bq + i) * DIM;
    a2[row + c0 + l31] = f2hu(o0[r] * inv);
    a2[row + c0 + l31 + 32] = f2hu(o1[r] * inv);
  }
}

// ---------------------------------------------------------------------------
extern "C" void kernel_launch(void* const* d_in, const int* in_sizes, int n_in,
                              void* d_out, int out_size, void* d_ws,
                              size_t ws_size, hipStream_t stream) {
  const float* x = (const float*)d_in[0];
  const float* w_qkv = (const float*)d_in[1];
  const float* w_proj = (const float*)d_in[2];
  const float* b_proj = (const float*)d_in[3];
  float* out = (float*)d_out;

  unsigned short* W1t = (unsigned short*)d_ws;      // [2304][768]
  unsigned short* W2t = W1t + (size_t)2304 * 768;   // [768][768]
  unsigned short* A1 = W2t + (size_t)768 * 768;     // [8192][768] (also attn out)
  unsigned short* q = A1 + (size_t)8192 * 768;      // [96][1024][64]
  unsigned short* k = q + (size_t)96 * 65536;       // [96][1024][64]
  unsigned short* vt = k + (size_t)96 * 65536;      // [96][64][1024]

  const int M = BATCH * SEQ;  // 8192

  prep_x<<<6144, 256, 0, stream>>>(x, A1);
  prep_wt<<<dim3(24, 72), 256, 0, stream>>>(w_qkv, W1t, 3 * DIM);
  prep_wt<<<dim3(24, 24), 256, 0, stream>>>(w_proj, W2t, DIM);

  // qkv = A1 x W1t^T, epilogue splits into q(scaled)/k/vt
  gemm_f16<1><<<dim3(18, M / 128), 256, 0, stream>>>(A1, W1t, nullptr, nullptr,
                                                     q, k, vt, 0);

  // attention -> A1 (reused as A2)
  attn<<<dim3(8, 96), 256, 0, stream>>>(q, k, vt, A1);

  // out = A2 x W2t^T + bias
  gemm_f16<0><<<dim3(6, M / 128), 256, 0, stream>>>(A1, W2t, b_proj, out,
                                                    nullptr, nullptr, nullptr,
                                                    DIM);
}

// Round 6
// 206.330 us; speedup vs baseline: 1.6372x; 1.0048x over previous
//
#include <hip/hip_runtime.h>
#include <cstdint>

#define DIM 768
#define NHEAD 12
#define SEQ 1024
#define BATCH 8

typedef _Float16 f16x8 __attribute__((ext_vector_type(8)));
typedef __attribute__((ext_vector_type(4))) float f32x4;
typedef __attribute__((ext_vector_type(16))) float f32x16;

__device__ __forceinline__ unsigned short f2hu(float f) {
  union { _Float16 h; unsigned short u; } x;
  x.h = (_Float16)f;
  return x.u;
}
__device__ __forceinline__ unsigned int pk2(float a, float b) {
  union { _Float16 h[2]; unsigned int u; } x;
  x.h[0] = (_Float16)a;
  x.h[1] = (_Float16)b;
  return x.u;
}
__device__ __forceinline__ void gl_lds16(const void* g, void* l) {
  __builtin_amdgcn_global_load_lds(
      (const __attribute__((address_space(1))) unsigned int*)g,
      (__attribute__((address_space(3))) unsigned int*)l, 16, 0, 0);
}

// ---------------------------------------------------------------------------
// prep_x: x fp32 [8192][768] -> A1 fp16 [8192][768]
// ---------------------------------------------------------------------------
__global__ __launch_bounds__(256) void prep_x(const float* __restrict__ x,
                                              unsigned short* __restrict__ a1) {
  int gid = blockIdx.x * 256 + threadIdx.x;  // 8192*192
  int m = gid / 192;
  int c = (gid % 192) * 4;
  float4 v = *(const float4*)&x[(size_t)m * DIM + c];
  *(uint2*)&a1[(size_t)m * DIM + c] = make_uint2(pk2(v.x, v.y), pk2(v.z, v.w));
}

// ---------------------------------------------------------------------------
// prep_w: both weights fp32 [768][N] -> fp16 [N][768] (transposed), one launch
// ---------------------------------------------------------------------------
__global__ __launch_bounds__(256) void prep_w(const float* __restrict__ wqkv,
                                              const float* __restrict__ wproj,
                                              unsigned short* __restrict__ W1t,
                                              unsigned short* __restrict__ W2t) {
  __shared__ float tile[32][33];
  const int by = blockIdx.y;
  const float* w;
  unsigned short* wt;
  int N, nt;
  if (by < 72) {
    w = wqkv; wt = W1t; N = 3 * DIM; nt = by * 32;
  } else {
    w = wproj; wt = W2t; N = DIM; nt = (by - 72) * 32;
  }
  const int kt = blockIdx.x * 32;
  const int t = threadIdx.x;
  const int c = t & 31, r8 = t >> 5;
#pragma unroll
  for (int p = 0; p < 4; ++p) {
    int k = kt + p * 8 + r8;
    tile[c][p * 8 + r8] = w[(size_t)k * N + nt + c];
  }
  __syncthreads();
#pragma unroll
  for (int p = 0; p < 4; ++p) {
    int nl = p * 8 + r8;
    wt[(size_t)(nt + nl) * DIM + kt + c] = f2hu(tile[nl][c]);
  }
}

// ---------------------------------------------------------------------------
// fp16 GEMM (m97 structure): C[M,N] = A[M,768] x Bt[N,768]^T.
// 128x128 tile, BK=64, 4 waves (2x2), 16x16x32 MFMA, XOR-swizzled LDS,
// global_load_lds width-16 staging with pre-permuted source.
// XCD-chunked block remap (T1): lin -> swz gives each XCD 8 contiguous
// M-rows (8 A-panels + all B-panels ~= L2-resident). nwg % 8 == 0 in both
// instantiations -> remap provably bijective.
// EPI 0: fp32 C + bias. EPI 1: QKV epilogue -> q(scaled)/k/vt fp16.
// ---------------------------------------------------------------------------
template <int EPI>
__global__ __launch_bounds__(256) void gemm_f16(
    const unsigned short* __restrict__ A, const unsigned short* __restrict__ Bt,
    const float* __restrict__ bias, float* __restrict__ C,
    unsigned short* __restrict__ q, unsigned short* __restrict__ k,
    unsigned short* __restrict__ vt, int N) {
  __shared__ char As[16384];  // 128 rows x 128 B
  __shared__ char Bs[16384];
  const int t = threadIdx.x;
  const int l = t & 63, wv = t >> 6;
  const int g = l >> 4, l15 = l & 15;
  const int wr = wv >> 1, wc = wv & 1;

  // XCD-chunked tile remap (dispatch order: blockIdx.x fastest -> lin%8 = XCD)
  const int gx = (EPI == 1) ? 18 : 6;
  const int nwg = gx * 64;
  const int lin = blockIdx.y * gx + blockIdx.x;
  const int cpx = nwg >> 3;
  const int swz = (lin & 7) * cpx + (lin >> 3);
  const int tn = swz % gx, tm = swz / gx;
  const int m0 = tm * 128, n0 = tn * 128;

  f32x4 acc[4][4];
#pragma unroll
  for (int i = 0; i < 4; ++i)
#pragma unroll
    for (int j = 0; j < 4; ++j)
#pragma unroll
      for (int r = 0; r < 4; ++r) acc[i][j][r] = 0.f;

  const int rowr = t >> 3;                    // 0..31
  const int dc = ((t & 7) ^ (rowr & 7)) * 8;  // swizzled source offset (elems)

  for (int k0 = 0; k0 < DIM; k0 += 64) {
    __syncthreads();
#pragma unroll
    for (int p = 0; p < 4; ++p) {
      int row = p * 32 + rowr;
      gl_lds16(A + (size_t)(m0 + row) * DIM + k0 + dc, As + p * 4096 + wv * 1024);
      gl_lds16(Bt + (size_t)(n0 + row) * DIM + k0 + dc, Bs + p * 4096 + wv * 1024);
    }
    __syncthreads();
#pragma unroll
    for (int ks = 0; ks < 2; ++ks) {
      f16x8 af[4], bfr[4];
#pragma unroll
      for (int mf = 0; mf < 4; ++mf) {
        int row = wr * 64 + mf * 16 + l15;
        af[mf] = *(const f16x8*)(As + row * 128 + ((ks * 4 + g) ^ (row & 7)) * 16);
      }
#pragma unroll
      for (int nf = 0; nf < 4; ++nf) {
        int row = wc * 64 + nf * 16 + l15;
        bfr[nf] = *(const f16x8*)(Bs + row * 128 + ((ks * 4 + g) ^ (row & 7)) * 16);
      }
#pragma unroll
      for (int mf = 0; mf < 4; ++mf)
#pragma unroll
        for (int nf = 0; nf < 4; ++nf)
          acc[mf][nf] = __builtin_amdgcn_mfma_f32_16x16x32_f16(
              af[mf], bfr[nf], acc[mf][nf], 0, 0, 0);
    }
  }

  if (EPI == 0) {
#pragma unroll
    for (int mf = 0; mf < 4; ++mf) {
      int row = m0 + wr * 64 + mf * 16 + g * 4;
#pragma unroll
      for (int nf = 0; nf < 4; ++nf) {
        int col = n0 + wc * 64 + nf * 16 + l15;
        float bb = bias[col];
#pragma unroll
        for (int r = 0; r < 4; ++r)
          C[(size_t)(row + r) * N + col] = acc[mf][nf][r] + bb;
      }
    }
  } else {
    const int region = tn / 6;  // 0=q, 1=k, 2=v (from swizzled tile coord!)
    const int colr0 = (tn % 6) * 128;
#pragma unroll
    for (int mf = 0; mf < 4; ++mf) {
      int m = m0 + wr * 64 + mf * 16 + g * 4;
      int b = m >> 10, ns = m & 1023;
#pragma unroll
      for (int nf = 0; nf < 4; ++nf) {
        int colr = colr0 + wc * 64 + nf * 16 + l15;
        int hh = colr >> 6, d = colr & 63;
        size_t base = ((size_t)(b * NHEAD + hh)) << 16;
        if (region == 0) {
#pragma unroll
          for (int r = 0; r < 4; ++r)
            q[base + ((size_t)(ns + r) << 6) + d] = f2hu(acc[mf][nf][r] * 0.125f);
        } else if (region == 1) {
#pragma unroll
          for (int r = 0; r < 4; ++r)
            k[base + ((size_t)(ns + r) << 6) + d] = f2hu(acc[mf][nf][r]);
        } else {
          *(uint2*)(vt + base + ((size_t)d << 10) + ns) =
              make_uint2(pk2(acc[mf][nf][0], acc[mf][nf][1]),
                         pk2(acc[mf][nf][2], acc[mf][nf][3]));
        }
      }
    }
  }
}

// ---------------------------------------------------------------------------
// Taylor attention, fp16. Grid (x=96 heads, y=8 q-blocks): same-head blocks
// stride 96 = 0 mod 8 -> same XCD -> K/V L2-resident per head.
// 2-phase double-buffered K/V staging: prefetch tile kt+1 under compute of kt,
// one barrier per tile (compiler drains vmcnt before s_barrier).
// ---------------------------------------------------------------------------
__global__ __launch_bounds__(256) void attn(
    const unsigned short* __restrict__ q, const unsigned short* __restrict__ k,
    const unsigned short* __restrict__ vt, unsigned short* __restrict__ a2) {
  __shared__ char KH[2][8192], VT[2][8192];  // [64 rows][128 B], swizzled
  __shared__ float DEN[4][32];
  const int t = threadIdx.x;
  const int l = t & 63, wv = t >> 6;
  const int h = l >> 5, l31 = l & 31;
  const int bh = blockIdx.x;                     // head index (XCD-local set)
  const int q0 = blockIdx.y * 128 + wv * 32;
  const size_t hb = ((size_t)bh) << 16;

  f16x8 qf[4];
#pragma unroll
  for (int ks = 0; ks < 4; ++ks)
    qf[ks] = *(const f16x8*)(q + hb + ((size_t)(q0 + l31) << 6) + ks * 16 + h * 8);

  f32x16 o0, o1;
#pragma unroll
  for (int r = 0; r < 16; ++r) { o0[r] = 0.f; o1[r] = 0.f; }
  float den = 0.f;

  const int rowr = t >> 3;
  const int dc = ((t & 7) ^ (rowr & 7)) * 8;

#define STAGE(buf, j0)                                                        \
  {                                                                           \
    _Pragma("unroll") for (int p = 0; p < 2; ++p) {                           \
      int row = p * 32 + rowr;                                                \
      gl_lds16(k + hb + ((size_t)((j0) + row) << 6) + dc,                     \
               KH[buf] + p * 4096 + wv * 1024);                               \
      gl_lds16(vt + hb + ((size_t)row << 10) + (j0) + dc,                     \
               VT[buf] + p * 4096 + wv * 1024);                               \
    }                                                                         \
  }

  STAGE(0, 0);
  __syncthreads();

  int buf = 0;
  for (int kt = 0; kt < 16; ++kt) {
    if (kt < 15) STAGE(buf ^ 1, (kt + 1) * 64);

    // S' = K . Q^T (rows j, cols i)
    f32x16 sf0, sf1;
#pragma unroll
    for (int r = 0; r < 16; ++r) { sf0[r] = 0.f; sf1[r] = 0.f; }
#pragma unroll
    for (int ks = 0; ks < 4; ++ks) {
      const int ch = ((2 * ks + h) ^ (l31 & 7)) * 16;
      sf0 = __builtin_amdgcn_mfma_f32_32x32x16_f16(
          *(const f16x8*)(KH[buf] + l31 * 128 + ch), qf[ks], sf0, 0, 0, 0);
      sf1 = __builtin_amdgcn_mfma_f32_32x32x16_f16(
          *(const f16x8*)(KH[buf] + (32 + l31) * 128 + ch), qf[ks], sf1, 0, 0, 0);
    }

    // f(s) = 1 + s + 0.5 s^2 (>= 0.5, ReLU no-op); pack to fp16 pairs
    unsigned int qw[8][2];
#pragma unroll
    for (int jf = 0; jf < 2; ++jf) {
#pragma unroll
      for (int qd = 0; qd < 4; ++qd) {
        float f[4];
#pragma unroll
        for (int e = 0; e < 4; ++e) {
          float s = (jf == 0) ? sf0[qd * 4 + e] : sf1[qd * 4 + e];
          f[e] = fmaf(s, fmaf(s, 0.5f, 1.0f), 1.0f);
          den += f[e];
        }
        qw[jf * 4 + qd][0] = pk2(f[0], f[1]);
        qw[jf * 4 + qd][1] = pk2(f[2], f[3]);
      }
    }

    // PV: assemble A-fragment via half-swap, multiply with transposed V tile
#pragma unroll
    for (int ks = 0; ks < 4; ++ks) {
      unsigned int u00 = qw[2 * ks][0], u01 = qw[2 * ks][1];
      unsigned int u10 = qw[2 * ks + 1][0], u11 = qw[2 * ks + 1][1];
      unsigned int s00 = (unsigned)__shfl_xor((int)u00, 32, 64);
      unsigned int s01 = (unsigned)__shfl_xor((int)u01, 32, 64);
      unsigned int s10 = (unsigned)__shfl_xor((int)u10, 32, 64);
      unsigned int s11 = (unsigned)__shfl_xor((int)u11, 32, 64);
      union { unsigned int u[4]; f16x8 v; } pu;
      pu.u[0] = h ? s10 : u00;
      pu.u[1] = h ? s11 : u01;
      pu.u[2] = h ? u10 : s00;
      pu.u[3] = h ? u11 : s01;
      const int ch = ((2 * ks + h) ^ (l31 & 7)) * 16;
      o0 = __builtin_amdgcn_mfma_f32_32x32x16_f16(
          pu.v, *(const f16x8*)(VT[buf] + l31 * 128 + ch), o0, 0, 0, 0);
      o1 = __builtin_amdgcn_mfma_f32_32x32x16_f16(
          pu.v, *(const f16x8*)(VT[buf] + (32 + l31) * 128 + ch), o1, 0, 0, 0);
    }

    __syncthreads();
    buf ^= 1;
  }

  // denominator: combine halves; DEN exchange is wave-internal (no barrier)
  den += __shfl_xor(den, 32, 64);
  if (h == 0) DEN[wv][l31] = den;

  const int bq = (bh / NHEAD) * SEQ + q0;
  const int c0 = (bh % NHEAD) * 64;
#pragma unroll
  for (int r = 0; r < 16; ++r) {
    const int i = (r & 3) + 8 * (r >> 2) + 4 * h;
    const float inv = 1.0f / DEN[wv][i];
    const size_t row = (size_t)(bq + i) * DIM;
    a2[row + c0 + l31] = f2hu(o0[r] * inv);
    a2[row + c0 + l31 + 32] = f2hu(o1[r] * inv);
  }
}

// ---------------------------------------------------------------------------
extern "C" void kernel_launch(void* const* d_in, const int* in_sizes, int n_in,
                              void* d_out, int out_size, void* d_ws,
                              size_t ws_size, hipStream_t stream) {
  const float* x = (const float*)d_in[0];
  const float* w_qkv = (const float*)d_in[1];
  const float* w_proj = (const float*)d_in[2];
  const float* b_proj = (const float*)d_in[3];
  float* out = (float*)d_out;

  unsigned short* W1t = (unsigned short*)d_ws;      // [2304][768]
  unsigned short* W2t = W1t + (size_t)2304 * 768;   // [768][768]
  unsigned short* A1 = W2t + (size_t)768 * 768;     // [8192][768] (also attn out)
  unsigned short* q = A1 + (size_t)8192 * 768;      // [96][1024][64]
  unsigned short* k = q + (size_t)96 * 65536;       // [96][1024][64]
  unsigned short* vt = k + (size_t)96 * 65536;      // [96][64][1024]

  const int M = BATCH * SEQ;  // 8192

  prep_x<<<6144, 256, 0, stream>>>(x, A1);
  prep_w<<<dim3(24, 96), 256, 0, stream>>>(w_qkv, w_proj, W1t, W2t);

  // qkv = A1 x W1t^T, epilogue splits into q(scaled)/k/vt
  gemm_f16<1><<<dim3(18, M / 128), 256, 0, stream>>>(A1, W1t, nullptr, nullptr,
                                                     q, k, vt, 0);

  // attention -> A1 (reused as A2); grid transposed for XCD locality
  attn<<<dim3(96, 8), 256, 0, stream>>>(q, k, vt, A1);

  // out = A2 x W2t^T + bias
  gemm_f16<0><<<dim3(6, M / 128), 256, 0, stream>>>(A1, W2t, b_proj, out,
                                                    nullptr, nullptr, nullptr,
                                                    DIM);
}

// Round 7
// 201.184 us; speedup vs baseline: 1.6790x; 1.0256x over previous
//
#include <hip/hip_runtime.h>
#include <cstdint>

#define DIM 768
#define NHEAD 12
#define SEQ 1024
#define BATCH 8

typedef _Float16 f16x8 __attribute__((ext_vector_type(8)));
typedef __attribute__((ext_vector_type(4))) float f32x4;
typedef __attribute__((ext_vector_type(16))) float f32x16;

__device__ __forceinline__ unsigned short f2hu(float f) {
  union { _Float16 h; unsigned short u; } x;
  x.h = (_Float16)f;
  return x.u;
}
__device__ __forceinline__ unsigned int pk2(float a, float b) {
  union { _Float16 h[2]; unsigned int u; } x;
  x.h[0] = (_Float16)a;
  x.h[1] = (_Float16)b;
  return x.u;
}
__device__ __forceinline__ void gl_lds16(const void* g, void* l) {
  __builtin_amdgcn_global_load_lds(
      (const __attribute__((address_space(1))) unsigned int*)g,
      (__attribute__((address_space(3))) unsigned int*)l, 16, 0, 0);
}

// ---------------------------------------------------------------------------
// prep_x: x fp32 [8192][768] -> A1 fp16 [8192][768]
// ---------------------------------------------------------------------------
__global__ __launch_bounds__(256) void prep_x(const float* __restrict__ x,
                                              unsigned short* __restrict__ a1) {
  int gid = blockIdx.x * 256 + threadIdx.x;  // 8192*192
  int m = gid / 192;
  int c = (gid % 192) * 4;
  float4 v = *(const float4*)&x[(size_t)m * DIM + c];
  *(uint2*)&a1[(size_t)m * DIM + c] = make_uint2(pk2(v.x, v.y), pk2(v.z, v.w));
}

// ---------------------------------------------------------------------------
// prep_w: both weights fp32 [768][N] -> fp16 [N][768] (transposed), one launch
// ---------------------------------------------------------------------------
__global__ __launch_bounds__(256) void prep_w(const float* __restrict__ wqkv,
                                              const float* __restrict__ wproj,
                                              unsigned short* __restrict__ W1t,
                                              unsigned short* __restrict__ W2t) {
  __shared__ float tile[32][33];
  const int by = blockIdx.y;
  const float* w;
  unsigned short* wt;
  int N, nt;
  if (by < 72) {
    w = wqkv; wt = W1t; N = 3 * DIM; nt = by * 32;
  } else {
    w = wproj; wt = W2t; N = DIM; nt = (by - 72) * 32;
  }
  const int kt = blockIdx.x * 32;
  const int t = threadIdx.x;
  const int c = t & 31, r8 = t >> 5;
#pragma unroll
  for (int p = 0; p < 4; ++p) {
    int k = kt + p * 8 + r8;
    tile[c][p * 8 + r8] = w[(size_t)k * N + nt + c];
  }
  __syncthreads();
#pragma unroll
  for (int p = 0; p < 4; ++p) {
    int nl = p * 8 + r8;
    wt[(size_t)(nt + nl) * DIM + kt + c] = f2hu(tile[nl][c]);
  }
}

// ---------------------------------------------------------------------------
// fp16 GEMM (m97 structure): C[M,N] = A[M,768] x Bt[N,768]^T.
// BMx128 tile (BM=128 for QKV, BM=64 for proj -> 2x blocks, lower VGPR,
// better TLP for the latency-bound regime), BK=64, 4 waves (2x2),
// 16x16x32 MFMA, XOR-swizzled LDS, global_load_lds width-16 staging.
// XCD-chunked block remap (T1); nwg % 8 == 0 in both instantiations.
// EPI 0: fp32 C + bias. EPI 1: QKV epilogue -> q(scaled)/k/vt fp16.
// ---------------------------------------------------------------------------
template <int EPI, int BM>
__global__ __launch_bounds__(256) void gemm_f16(
    const unsigned short* __restrict__ A, const unsigned short* __restrict__ Bt,
    const float* __restrict__ bias, float* __restrict__ C,
    unsigned short* __restrict__ q, unsigned short* __restrict__ k,
    unsigned short* __restrict__ vt, int N) {
  constexpr int MF = BM / 32;  // m-fragments per wave (wave covers BM/2 rows)
  __shared__ char As[BM * 128];  // BM rows x 128 B
  __shared__ char Bs[16384];     // 128 rows x 128 B
  const int t = threadIdx.x;
  const int l = t & 63, wv = t >> 6;
  const int g = l >> 4, l15 = l & 15;
  const int wr = wv >> 1, wc = wv & 1;

  // XCD-chunked tile remap (dispatch order: blockIdx.x fastest -> lin%8 = XCD)
  const int gx = (EPI == 1) ? 18 : 6;
  const int nwg = gx * (8192 / BM);
  const int lin = blockIdx.y * gx + blockIdx.x;
  const int cpx = nwg >> 3;
  const int swz = (lin & 7) * cpx + (lin >> 3);
  const int tn = swz % gx, tm = swz / gx;
  const int m0 = tm * BM, n0 = tn * 128;

  f32x4 acc[MF][4];
#pragma unroll
  for (int i = 0; i < MF; ++i)
#pragma unroll
    for (int j = 0; j < 4; ++j)
#pragma unroll
      for (int r = 0; r < 4; ++r) acc[i][j][r] = 0.f;

  const int rowr = t >> 3;                    // 0..31
  const int dc = ((t & 7) ^ (rowr & 7)) * 8;  // swizzled source offset (elems)

  for (int k0 = 0; k0 < DIM; k0 += 64) {
    __syncthreads();
#pragma unroll
    for (int p = 0; p < BM / 32; ++p) {
      int row = p * 32 + rowr;
      gl_lds16(A + (size_t)(m0 + row) * DIM + k0 + dc, As + p * 4096 + wv * 1024);
    }
#pragma unroll
    for (int p = 0; p < 4; ++p) {
      int row = p * 32 + rowr;
      gl_lds16(Bt + (size_t)(n0 + row) * DIM + k0 + dc, Bs + p * 4096 + wv * 1024);
    }
    __syncthreads();
#pragma unroll
    for (int ks = 0; ks < 2; ++ks) {
      f16x8 af[MF], bfr[4];
#pragma unroll
      for (int mf = 0; mf < MF; ++mf) {
        int row = wr * (BM / 2) + mf * 16 + l15;
        af[mf] = *(const f16x8*)(As + row * 128 + ((ks * 4 + g) ^ (row & 7)) * 16);
      }
#pragma unroll
      for (int nf = 0; nf < 4; ++nf) {
        int row = wc * 64 + nf * 16 + l15;
        bfr[nf] = *(const f16x8*)(Bs + row * 128 + ((ks * 4 + g) ^ (row & 7)) * 16);
      }
#pragma unroll
      for (int mf = 0; mf < MF; ++mf)
#pragma unroll
        for (int nf = 0; nf < 4; ++nf)
          acc[mf][nf] = __builtin_amdgcn_mfma_f32_16x16x32_f16(
              af[mf], bfr[nf], acc[mf][nf], 0, 0, 0);
    }
  }

  if (EPI == 0) {
#pragma unroll
    for (int mf = 0; mf < MF; ++mf) {
      int row = m0 + wr * (BM / 2) + mf * 16 + g * 4;
#pragma unroll
      for (int nf = 0; nf < 4; ++nf) {
        int col = n0 + wc * 64 + nf * 16 + l15;
        float bb = bias[col];
#pragma unroll
        for (int r = 0; r < 4; ++r)
          C[(size_t)(row + r) * N + col] = acc[mf][nf][r] + bb;
      }
    }
  } else {
    const int region = tn / 6;  // 0=q, 1=k, 2=v (from swizzled tile coord!)
    const int colr0 = (tn % 6) * 128;
#pragma unroll
    for (int mf = 0; mf < MF; ++mf) {
      int m = m0 + wr * (BM / 2) + mf * 16 + g * 4;
      int b = m >> 10, ns = m & 1023;
#pragma unroll
      for (int nf = 0; nf < 4; ++nf) {
        int colr = colr0 + wc * 64 + nf * 16 + l15;
        int hh = colr >> 6, d = colr & 63;
        size_t base = ((size_t)(b * NHEAD + hh)) << 16;
        if (region == 0) {
#pragma unroll
          for (int r = 0; r < 4; ++r)
            q[base + ((size_t)(ns + r) << 6) + d] = f2hu(acc[mf][nf][r] * 0.125f);
        } else if (region == 1) {
#pragma unroll
          for (int r = 0; r < 4; ++r)
            k[base + ((size_t)(ns + r) << 6) + d] = f2hu(acc[mf][nf][r]);
        } else {
          *(uint2*)(vt + base + ((size_t)d << 10) + ns) =
              make_uint2(pk2(acc[mf][nf][0], acc[mf][nf][1]),
                         pk2(acc[mf][nf][2], acc[mf][nf][3]));
        }
      }
    }
  }
}

// ---------------------------------------------------------------------------
// Taylor attention, fp16. Grid (x=96 heads, y=8 q-blocks): same-head blocks
// stride 96 = 0 mod 8 -> same XCD -> K/V L2-resident per head.
// 2-phase double-buffered K/V staging: prefetch tile kt+1 under compute of kt,
// one barrier per tile (compiler drains vmcnt before s_barrier).
// ---------------------------------------------------------------------------
__global__ __launch_bounds__(256) void attn(
    const unsigned short* __restrict__ q, const unsigned short* __restrict__ k,
    const unsigned short* __restrict__ vt, unsigned short* __restrict__ a2) {
  __shared__ char KH[2][8192], VT[2][8192];  // [64 rows][128 B], swizzled
  __shared__ float DEN[4][32];
  const int t = threadIdx.x;
  const int l = t & 63, wv = t >> 6;
  const int h = l >> 5, l31 = l & 31;
  const int bh = blockIdx.x;                     // head index (XCD-local set)
  const int q0 = blockIdx.y * 128 + wv * 32;
  const size_t hb = ((size_t)bh) << 16;

  f16x8 qf[4];
#pragma unroll
  for (int ks = 0; ks < 4; ++ks)
    qf[ks] = *(const f16x8*)(q + hb + ((size_t)(q0 + l31) << 6) + ks * 16 + h * 8);

  f32x16 o0, o1;
#pragma unroll
  for (int r = 0; r < 16; ++r) { o0[r] = 0.f; o1[r] = 0.f; }
  float den = 0.f;

  const int rowr = t >> 3;
  const int dc = ((t & 7) ^ (rowr & 7)) * 8;

#define STAGE(buf, j0)                                                        \
  {                                                                           \
    _Pragma("unroll") for (int p = 0; p < 2; ++p) {                           \
      int row = p * 32 + rowr;                                                \
      gl_lds16(k + hb + ((size_t)((j0) + row) << 6) + dc,                     \
               KH[buf] + p * 4096 + wv * 1024);                               \
      gl_lds16(vt + hb + ((size_t)row << 10) + (j0) + dc,                     \
               VT[buf] + p * 4096 + wv * 1024);                               \
    }                                                                         \
  }

  STAGE(0, 0);
  __syncthreads();

  int buf = 0;
  for (int kt = 0; kt < 16; ++kt) {
    if (kt < 15) STAGE(buf ^ 1, (kt + 1) * 64);

    // S' = K . Q^T (rows j, cols i)
    f32x16 sf0, sf1;
#pragma unroll
    for (int r = 0; r < 16; ++r) { sf0[r] = 0.f; sf1[r] = 0.f; }
#pragma unroll
    for (int ks = 0; ks < 4; ++ks) {
      const int ch = ((2 * ks + h) ^ (l31 & 7)) * 16;
      sf0 = __builtin_amdgcn_mfma_f32_32x32x16_f16(
          *(const f16x8*)(KH[buf] + l31 * 128 + ch), qf[ks], sf0, 0, 0, 0);
      sf1 = __builtin_amdgcn_mfma_f32_32x32x16_f16(
          *(const f16x8*)(KH[buf] + (32 + l31) * 128 + ch), qf[ks], sf1, 0, 0, 0);
    }

    // f(s) = 1 + s + 0.5 s^2 (>= 0.5, ReLU no-op); pack to fp16 pairs
    unsigned int qw[8][2];
#pragma unroll
    for (int jf = 0; jf < 2; ++jf) {
#pragma unroll
      for (int qd = 0; qd < 4; ++qd) {
        float f[4];
#pragma unroll
        for (int e = 0; e < 4; ++e) {
          float s = (jf == 0) ? sf0[qd * 4 + e] : sf1[qd * 4 + e];
          f[e] = fmaf(s, fmaf(s, 0.5f, 1.0f), 1.0f);
          den += f[e];
        }
        qw[jf * 4 + qd][0] = pk2(f[0], f[1]);
        qw[jf * 4 + qd][1] = pk2(f[2], f[3]);
      }
    }

    // PV: assemble A-fragment via half-swap, multiply with transposed V tile
#pragma unroll
    for (int ks = 0; ks < 4; ++ks) {
      unsigned int u00 = qw[2 * ks][0], u01 = qw[2 * ks][1];
      unsigned int u10 = qw[2 * ks + 1][0], u11 = qw[2 * ks + 1][1];
      unsigned int s00 = (unsigned)__shfl_xor((int)u00, 32, 64);
      unsigned int s01 = (unsigned)__shfl_xor((int)u01, 32, 64);
      unsigned int s10 = (unsigned)__shfl_xor((int)u10, 32, 64);
      unsigned int s11 = (unsigned)__shfl_xor((int)u11, 32, 64);
      union { unsigned int u[4]; f16x8 v; } pu;
      pu.u[0] = h ? s10 : u00;
      pu.u[1] = h ? s11 : u01;
      pu.u[2] = h ? u10 : s00;
      pu.u[3] = h ? u11 : s01;
      const int ch = ((2 * ks + h) ^ (l31 & 7)) * 16;
      o0 = __builtin_amdgcn_mfma_f32_32x32x16_f16(
          pu.v, *(const f16x8*)(VT[buf] + l31 * 128 + ch), o0, 0, 0, 0);
      o1 = __builtin_amdgcn_mfma_f32_32x32x16_f16(
          pu.v, *(const f16x8*)(VT[buf] + (32 + l31) * 128 + ch), o1, 0, 0, 0);
    }

    __syncthreads();
    buf ^= 1;
  }

  // denominator: combine halves; DEN exchange is wave-internal (no barrier)
  den += __shfl_xor(den, 32, 64);
  if (h == 0) DEN[wv][l31] = den;

  const int bq = (bh / NHEAD) * SEQ + q0;
  const int c0 = (bh % NHEAD) * 64;
#pragma unroll
  for (int r = 0; r < 16; ++r) {
    const int i = (r & 3) + 8 * (r >> 2) + 4 * h;
    const float inv = 1.0f / DEN[wv][i];
    const size_t row = (size_t)(bq + i) * DIM;
    a2[row + c0 + l31] = f2hu(o0[r] * inv);
    a2[row + c0 + l31 + 32] = f2hu(o1[r] * inv);
  }
}

// ---------------------------------------------------------------------------
extern "C" void kernel_launch(void* const* d_in, const int* in_sizes, int n_in,
                              void* d_out, int out_size, void* d_ws,
                              size_t ws_size, hipStream_t stream) {
  const float* x = (const float*)d_in[0];
  const float* w_qkv = (const float*)d_in[1];
  const float* w_proj = (const float*)d_in[2];
  const float* b_proj = (const float*)d_in[3];
  float* out = (float*)d_out;

  unsigned short* W1t = (unsigned short*)d_ws;      // [2304][768]
  unsigned short* W2t = W1t + (size_t)2304 * 768;   // [768][768]
  unsigned short* A1 = W2t + (size_t)768 * 768;     // [8192][768] (also attn out)
  unsigned short* q = A1 + (size_t)8192 * 768;      // [96][1024][64]
  unsigned short* k = q + (size_t)96 * 65536;       // [96][1024][64]
  unsigned short* vt = k + (size_t)96 * 65536;      // [96][64][1024]

  const int M = BATCH * SEQ;  // 8192

  prep_x<<<6144, 256, 0, stream>>>(x, A1);
  prep_w<<<dim3(24, 96), 256, 0, stream>>>(w_qkv, w_proj, W1t, W2t);

  // qkv = A1 x W1t^T, epilogue splits into q(scaled)/k/vt
  gemm_f16<1, 128><<<dim3(18, M / 128), 256, 0, stream>>>(
      A1, W1t, nullptr, nullptr, q, k, vt, 0);

  // attention -> A1 (reused as A2); grid transposed for XCD locality
  attn<<<dim3(96, 8), 256, 0, stream>>>(q, k, vt, A1);

  // out = A2 x W2t^T + bias  (BM=64: 768 blocks, TLP for latency-bound regime)
  gemm_f16<0, 64><<<dim3(6, M / 64), 256, 0, stream>>>(
      A1, W2t, b_proj, out, nullptr, nullptr, nullptr, DIM);
}

// Round 9
// 189.495 us; speedup vs baseline: 1.7826x; 1.0617x over previous
//
#include <hip/hip_runtime.h>
#include <cstdint>

#define DIM 768
#define NHEAD 12
#define SEQ 1024
#define BATCH 8

typedef _Float16 f16x8 __attribute__((ext_vector_type(8)));
typedef __fp16 h16x2 __attribute__((ext_vector_type(2)));
typedef __attribute__((ext_vector_type(4))) float f32x4;
typedef __attribute__((ext_vector_type(16))) float f32x16;

__device__ __forceinline__ unsigned short f2hu(float f) {
  union { _Float16 h; unsigned short u; } x;
  x.h = (_Float16)f;
  return x.u;
}
__device__ __forceinline__ unsigned int pk2(float a, float b) {
  union { _Float16 h[2]; unsigned int u; } x;
  x.h[0] = (_Float16)a;
  x.h[1] = (_Float16)b;
  return x.u;
}
__device__ __forceinline__ void gl_lds16(const void* g, void* l) {
  __builtin_amdgcn_global_load_lds(
      (const __attribute__((address_space(1))) unsigned int*)g,
      (__attribute__((address_space(3))) unsigned int*)l, 16, 0, 0);
}

// ---------------------------------------------------------------------------
// prep_x: x fp32 [8192][768] -> A1 fp16 [8192][768]
// ---------------------------------------------------------------------------
__global__ __launch_bounds__(256) void prep_x(const float* __restrict__ x,
                                              unsigned short* __restrict__ a1) {
  int gid = blockIdx.x * 256 + threadIdx.x;  // 8192*192
  int m = gid / 192;
  int c = (gid % 192) * 4;
  float4 v = *(const float4*)&x[(size_t)m * DIM + c];
  *(uint2*)&a1[(size_t)m * DIM + c] = make_uint2(pk2(v.x, v.y), pk2(v.z, v.w));
}

// ---------------------------------------------------------------------------
// prep_w: both weights fp32 [768][N] -> fp16 [N][768] (transposed), one launch
// ---------------------------------------------------------------------------
__global__ __launch_bounds__(256) void prep_w(const float* __restrict__ wqkv,
                                              const float* __restrict__ wproj,
                                              unsigned short* __restrict__ W1t,
                                              unsigned short* __restrict__ W2t) {
  __shared__ float tile[32][33];
  const int by = blockIdx.y;
  const float* w;
  unsigned short* wt;
  int N, nt;
  if (by < 72) {
    w = wqkv; wt = W1t; N = 3 * DIM; nt = by * 32;
  } else {
    w = wproj; wt = W2t; N = DIM; nt = (by - 72) * 32;
  }
  const int kt = blockIdx.x * 32;
  const int t = threadIdx.x;
  const int c = t & 31, r8 = t >> 5;
#pragma unroll
  for (int p = 0; p < 4; ++p) {
    int k = kt + p * 8 + r8;
    tile[c][p * 8 + r8] = w[(size_t)k * N + nt + c];
  }
  __syncthreads();
#pragma unroll
  for (int p = 0; p < 4; ++p) {
    int nl = p * 8 + r8;
    wt[(size_t)(nt + nl) * DIM + kt + c] = f2hu(tile[nl][c]);
  }
}

// ---------------------------------------------------------------------------
// fp16 GEMM (m97 structure): C[M,N] = A[M,768] x Bt[N,768]^T.
// BMx128 tile (BM=128 for QKV, BM=64 for proj), BK=64, 4 waves (2x2),
// 16x16x32 MFMA, XOR-swizzled LDS, global_load_lds width-16 staging.
// XCD-chunked block remap (T1); nwg % 8 == 0 in both instantiations.
// EPI 0: fp32 C + bias. EPI 1: QKV epilogue -> q(scaled)/k/vt fp16.
// ---------------------------------------------------------------------------
template <int EPI, int BM>
__global__ __launch_bounds__(256) void gemm_f16(
    const unsigned short* __restrict__ A, const unsigned short* __restrict__ Bt,
    const float* __restrict__ bias, float* __restrict__ C,
    unsigned short* __restrict__ q, unsigned short* __restrict__ k,
    unsigned short* __restrict__ vt, int N) {
  constexpr int MF = BM / 32;  // m-fragments per wave (wave covers BM/2 rows)
  __shared__ char As[BM * 128];  // BM rows x 128 B
  __shared__ char Bs[16384];     // 128 rows x 128 B
  const int t = threadIdx.x;
  const int l = t & 63, wv = t >> 6;
  const int g = l >> 4, l15 = l & 15;
  const int wr = wv >> 1, wc = wv & 1;

  // XCD-chunked tile remap (dispatch order: blockIdx.x fastest -> lin%8 = XCD)
  const int gx = (EPI == 1) ? 18 : 6;
  const int nwg = gx * (8192 / BM);
  const int lin = blockIdx.y * gx + blockIdx.x;
  const int cpx = nwg >> 3;
  const int swz = (lin & 7) * cpx + (lin >> 3);
  const int tn = swz % gx, tm = swz / gx;
  const int m0 = tm * BM, n0 = tn * 128;

  f32x4 acc[MF][4];
#pragma unroll
  for (int i = 0; i < MF; ++i)
#pragma unroll
    for (int j = 0; j < 4; ++j)
#pragma unroll
      for (int r = 0; r < 4; ++r) acc[i][j][r] = 0.f;

  const int rowr = t >> 3;                    // 0..31
  const int dc = ((t & 7) ^ (rowr & 7)) * 8;  // swizzled source offset (elems)

  for (int k0 = 0; k0 < DIM; k0 += 64) {
    __syncthreads();
#pragma unroll
    for (int p = 0; p < BM / 32; ++p) {
      int row = p * 32 + rowr;
      gl_lds16(A + (size_t)(m0 + row) * DIM + k0 + dc, As + p * 4096 + wv * 1024);
    }
#pragma unroll
    for (int p = 0; p < 4; ++p) {
      int row = p * 32 + rowr;
      gl_lds16(Bt + (size_t)(n0 + row) * DIM + k0 + dc, Bs + p * 4096 + wv * 1024);
    }
    __syncthreads();
#pragma unroll
    for (int ks = 0; ks < 2; ++ks) {
      f16x8 af[MF], bfr[4];
#pragma unroll
      for (int mf = 0; mf < MF; ++mf) {
        int row = wr * (BM / 2) + mf * 16 + l15;
        af[mf] = *(const f16x8*)(As + row * 128 + ((ks * 4 + g) ^ (row & 7)) * 16);
      }
#pragma unroll
      for (int nf = 0; nf < 4; ++nf) {
        int row = wc * 64 + nf * 16 + l15;
        bfr[nf] = *(const f16x8*)(Bs + row * 128 + ((ks * 4 + g) ^ (row & 7)) * 16);
      }
#pragma unroll
      for (int mf = 0; mf < MF; ++mf)
#pragma unroll
        for (int nf = 0; nf < 4; ++nf)
          acc[mf][nf] = __builtin_amdgcn_mfma_f32_16x16x32_f16(
              af[mf], bfr[nf], acc[mf][nf], 0, 0, 0);
    }
  }

  if (EPI == 0) {
#pragma unroll
    for (int mf = 0; mf < MF; ++mf) {
      int row = m0 + wr * (BM / 2) + mf * 16 + g * 4;
#pragma unroll
      for (int nf = 0; nf < 4; ++nf) {
        int col = n0 + wc * 64 + nf * 16 + l15;
        float bb = bias[col];
#pragma unroll
        for (int r = 0; r < 4; ++r)
          C[(size_t)(row + r) * N + col] = acc[mf][nf][r] + bb;
      }
    }
  } else {
    const int region = tn / 6;  // 0=q, 1=k, 2=v (from swizzled tile coord!)
    const int colr0 = (tn % 6) * 128;
#pragma unroll
    for (int mf = 0; mf < MF; ++mf) {
      int m = m0 + wr * (BM / 2) + mf * 16 + g * 4;
      int b = m >> 10, ns = m & 1023;
#pragma unroll
      for (int nf = 0; nf < 4; ++nf) {
        int colr = colr0 + wc * 64 + nf * 16 + l15;
        int hh = colr >> 6, d = colr & 63;
        size_t base = ((size_t)(b * NHEAD + hh)) << 16;
        if (region == 0) {
#pragma unroll
          for (int r = 0; r < 4; ++r)
            q[base + ((size_t)(ns + r) << 6) + d] = f2hu(acc[mf][nf][r] * 0.125f);
        } else if (region == 1) {
#pragma unroll
          for (int r = 0; r < 4; ++r)
            k[base + ((size_t)(ns + r) << 6) + d] = f2hu(acc[mf][nf][r]);
        } else {
          *(uint2*)(vt + base + ((size_t)d << 10) + ns) =
              make_uint2(pk2(acc[mf][nf][0], acc[mf][nf][1]),
                         pk2(acc[mf][nf][2], acc[mf][nf][3]));
        }
      }
    }
  }
}

// ---------------------------------------------------------------------------
// Taylor attention, fp16, VALU-lean version.
//  - QK^T accumulator initialized to 1.0 -> MFMA emits t = s+1 directly.
//  - P' = t^2 + 1 = 2*(1 + s + s^2/2); the factor 2 cancels in normalization
//    (P' >= 1 > 0, ReLU still a provable no-op). One fma per element.
//  - v_cvt_pkrtz_f16_f32 packed converts (RTZ); den computed from the SAME
//    rounded P-hat via v_dot2_f32_f16 -> first-order ratio cancellation.
//  - v_permlane32_swap_b32 (D.hi <-> S.lo) assembles the PV A-fragment:
//    replaces 16 ds_bpermute shuffles + 16 cndmask with 8 VALU swaps.
// Grid (x=96 heads, y=8 q-blocks) for per-head XCD/L2 locality; 2-phase
// double-buffered K/V staging.
// ---------------------------------------------------------------------------
__global__ __launch_bounds__(256) void attn(
    const unsigned short* __restrict__ q, const unsigned short* __restrict__ k,
    const unsigned short* __restrict__ vt, unsigned short* __restrict__ a2) {
  __shared__ char KH[2][8192], VT[2][8192];  // [64 rows][128 B], swizzled
  __shared__ float DEN[4][32];
  const int t = threadIdx.x;
  const int l = t & 63, wv = t >> 6;
  const int h = l >> 5, l31 = l & 31;
  const int bh = blockIdx.x;                     // head index (XCD-local set)
  const int q0 = blockIdx.y * 128 + wv * 32;
  const size_t hb = ((size_t)bh) << 16;

  f16x8 qf[4];
#pragma unroll
  for (int ks = 0; ks < 4; ++ks)
    qf[ks] = *(const f16x8*)(q + hb + ((size_t)(q0 + l31) << 6) + ks * 16 + h * 8);

  f32x16 o0, o1;
#pragma unroll
  for (int r = 0; r < 16; ++r) { o0[r] = 0.f; o1[r] = 0.f; }
  float den = 0.f;
  const h16x2 ones = {(__fp16)1.0f, (__fp16)1.0f};

  const int rowr = t >> 3;
  const int dc = ((t & 7) ^ (rowr & 7)) * 8;

#define STAGE(buf, j0)                                                        \
  {                                                                           \
    _Pragma("unroll") for (int p = 0; p < 2; ++p) {                           \
      int row = p * 32 + rowr;                                                \
      gl_lds16(k + hb + ((size_t)((j0) + row) << 6) + dc,                     \
               KH[buf] + p * 4096 + wv * 1024);                               \
      gl_lds16(vt + hb + ((size_t)row << 10) + (j0) + dc,                     \
               VT[buf] + p * 4096 + wv * 1024);                               \
    }                                                                         \
  }

  STAGE(0, 0);
  __syncthreads();

  int buf = 0;
  for (int kt = 0; kt < 16; ++kt) {
    if (kt < 15) STAGE(buf ^ 1, (kt + 1) * 64);

    // t = 1 + K.Q^T (rows j, cols i) via C-init = 1.0
    f32x16 sf0, sf1;
#pragma unroll
    for (int r = 0; r < 16; ++r) { sf0[r] = 1.f; sf1[r] = 1.f; }
#pragma unroll
    for (int ks = 0; ks < 4; ++ks) {
      const int ch = ((2 * ks + h) ^ (l31 & 7)) * 16;
      sf0 = __builtin_amdgcn_mfma_f32_32x32x16_f16(
          *(const f16x8*)(KH[buf] + l31 * 128 + ch), qf[ks], sf0, 0, 0, 0);
      sf1 = __builtin_amdgcn_mfma_f32_32x32x16_f16(
          *(const f16x8*)(KH[buf] + (32 + l31) * 128 + ch), qf[ks], sf1, 0, 0, 0);
    }

    // P' = t^2 + 1 (= 2*f, scale cancels in normalization); pack RTZ;
    // den from the packed values (ratio-consistent).
    unsigned int qw[8][2];
#pragma unroll
    for (int jf = 0; jf < 2; ++jf) {
#pragma unroll
      for (int qd = 0; qd < 4; ++qd) {
        float f[4];
#pragma unroll
        for (int e = 0; e < 4; ++e) {
          float s = (jf == 0) ? sf0[qd * 4 + e] : sf1[qd * 4 + e];
          f[e] = fmaf(s, s, 1.0f);
        }
        union { h16x2 h; unsigned u; } c0, c1;
        c0.h = __builtin_amdgcn_cvt_pkrtz(f[0], f[1]);
        c1.h = __builtin_amdgcn_cvt_pkrtz(f[2], f[3]);
        den = __builtin_amdgcn_fdot2(c0.h, ones, den, false);
        den = __builtin_amdgcn_fdot2(c1.h, ones, den, false);
        qw[jf * 4 + qd][0] = c0.u;
        qw[jf * 4 + qd][1] = c1.u;
      }
    }

    // PV: assemble A-fragment via permlane32_swap (D.hi <-> S.lo), multiply
    // with transposed V tile.
#pragma unroll
    for (int ks = 0; ks < 4; ++ks) {
      unsigned a0 = qw[2 * ks][0], b0 = qw[2 * ks + 1][0];
      unsigned a1 = qw[2 * ks][1], b1 = qw[2 * ks + 1][1];
      asm("v_permlane32_swap_b32 %0, %1" : "+v"(a0), "+v"(b0));
      asm("v_permlane32_swap_b32 %0, %1" : "+v"(a1), "+v"(b1));
      union { unsigned u[4]; f16x8 v; } pu;
      pu.u[0] = a0;
      pu.u[1] = a1;
      pu.u[2] = b0;
      pu.u[3] = b1;
      const int ch = ((2 * ks + h) ^ (l31 & 7)) * 16;
      o0 = __builtin_amdgcn_mfma_f32_32x32x16_f16(
          pu.v, *(const f16x8*)(VT[buf] + l31 * 128 + ch), o0, 0, 0, 0);
      o1 = __builtin_amdgcn_mfma_f32_32x32x16_f16(
          pu.v, *(const f16x8*)(VT[buf] + (32 + l31) * 128 + ch), o1, 0, 0, 0);
    }

    __syncthreads();
    buf ^= 1;
  }

  // denominator: combine halves; DEN exchange is wave-internal (no barrier)
  den += __shfl_xor(den, 32, 64);
  if (h == 0) DEN[wv][l31] = den;

  const int bq = (bh / NHEAD) * SEQ + q0;
  const int c0 = (bh % NHEAD) * 64;
#pragma unroll
  for (int r = 0; r < 16; ++r) {
    const int i = (r & 3) + 8 * (r >> 2) + 4 * h;
    const float inv = 1.0f / DEN[wv][i];
    const size_t row = (size_t)(bq + i) * DIM;
    a2[row + c0 + l31] = f2hu(o0[r] * inv);
    a2[row + c0 + l31 + 32] = f2hu(o1[r] * inv);
  }
}

// ---------------------------------------------------------------------------
extern "C" void kernel_launch(void* const* d_in, const int* in_sizes, int n_in,
                              void* d_out, int out_size, void* d_ws,
                              size_t ws_size, hipStream_t stream) {
  const float* x = (const float*)d_in[0];
  const float* w_qkv = (const float*)d_in[1];
  const float* w_proj = (const float*)d_in[2];
  const float* b_proj = (const float*)d_in[3];
  float* out = (float*)d_out;

  unsigned short* W1t = (unsigned short*)d_ws;      // [2304][768]
  unsigned short* W2t = W1t + (size_t)2304 * 768;   // [768][768]
  unsigned short* A1 = W2t + (size_t)768 * 768;     // [8192][768] (also attn out)
  unsigned short* q = A1 + (size_t)8192 * 768;      // [96][1024][64]
  unsigned short* k = q + (size_t)96 * 65536;       // [96][1024][64]
  unsigned short* vt = k + (size_t)96 * 65536;      // [96][64][1024]

  const int M = BATCH * SEQ;  // 8192

  prep_x<<<6144, 256, 0, stream>>>(x, A1);
  prep_w<<<dim3(24, 96), 256, 0, stream>>>(w_qkv, w_proj, W1t, W2t);

  // qkv = A1 x W1t^T, epilogue splits into q(scaled)/k/vt
  gemm_f16<1, 128><<<dim3(18, M / 128), 256, 0, stream>>>(
      A1, W1t, nullptr, nullptr, q, k, vt, 0);

  // attention -> A1 (reused as A2); grid transposed for XCD locality
  attn<<<dim3(96, 8), 256, 0, stream>>>(q, k, vt, A1);

  // out = A2 x W2t^T + bias  (BM=64: 768 blocks, TLP for latency-bound regime)
  gemm_f16<0, 64><<<dim3(6, M / 64), 256, 0, stream>>>(
      A1, W2t, b_proj, out, nullptr, nullptr, nullptr, DIM);
}